// Round 14
// baseline (547.510 us; speedup 1.0000x reference)
//
#include <hip/hip_runtime.h>
#include <hip/hip_bf16.h>
#include <hip/hip_fp16.h>

#define TT 24
#define FF 16
#define HH 64
#define GG 192   // 3*HH

typedef __attribute__((ext_vector_type(4))) float f32x4;
typedef __attribute__((ext_vector_type(8))) _Float16 f16x8;

__device__ __forceinline__ float fast_rcp(float x){ return __builtin_amdgcn_rcpf(x); }
__device__ __forceinline__ float sigmoid_f(float x){
  return fast_rcp(1.0f + __expf(-x));
}
__device__ __forceinline__ float tanh_f(float x){
  float e = __expf(-2.0f * fabsf(x));
  float th = (1.0f - e) * fast_rcp(1.0f + e);
  return copysignf(th, x);
}
__device__ __forceinline__ uint pack_h2(float a, float b){
  ushort ha = __half_as_ushort(__float2half(a));
  ushort hb = __half_as_ushort(__float2half(b));
  return (uint)ha | ((uint)hb << 16);
}
__device__ __forceinline__ void acc8(float* a, uint4 u, float w){
  __half2 p0 = *(__half2*)&u.x, p1 = *(__half2*)&u.y;
  __half2 p2 = *(__half2*)&u.z, p3 = *(__half2*)&u.w;
  float2 f0 = __half22float2(p0), f1 = __half22float2(p1);
  float2 f2 = __half22float2(p2), f3 = __half22float2(p3);
  a[0] += w*f0.x; a[1] += w*f0.y; a[2] += w*f1.x; a[3] += w*f1.y;
  a[4] += w*f2.x; a[5] += w*f2.y; a[6] += w*f3.x; a[7] += w*f3.y;
}
__device__ __forceinline__ void acc4(float* a, uint2 u, float w){
  __half2 p0 = *(__half2*)&u.x, p1 = *(__half2*)&u.y;
  float2 f0 = __half22float2(p0), f1 = __half22float2(p1);
  a[0] += w*f0.x; a[1] += w*f0.y; a[2] += w*f1.x; a[3] += w*f1.y;
}

// ---------------- fused prologue: xt2 || deg || prep ----------------
__global__ __launch_bounds__(256)
void k_pre(const float* __restrict__ x, ushort* __restrict__ xTh,
           const int* __restrict__ ei, int E, int* __restrict__ deg,
           const float* __restrict__ gcn_w, const float* __restrict__ gcn_b,
           const float* __restrict__ w_ih, const float* __restrict__ b_ih,
           const float* __restrict__ w_hh,
           ushort* __restrict__ m1F, float* __restrict__ c1, ushort* __restrict__ whhF,
           int N, int GX, int GD){
  __shared__ ushort tile[16][392];
  const int bid = blockIdx.x;
  const int tid = threadIdx.x;
  if(bid < GX){
    const int nbase = bid * 16;
    const int nd = tid >> 4, f = tid & 15;
    const int n = nbase + nd;
    for(int t=0; t<TT; t++){
      float v = (n < N) ? x[((size_t)t*N + n)*FF + f] : 0.f;
      tile[nd][t*16 + f] = __half_as_ushort(__float2half(v));
    }
    __syncthreads();
    uint* xo = (uint*)xTh;
    for(int i = tid; i < 16*192; i += 256){
      int d = i / 192, pos = i - d*192;
      int nn = nbase + d;
      if(nn < N) xo[(size_t)nn*192 + pos] = *(uint*)&tile[d][pos*2];
    }
  } else if(bid < GX + GD){
    int i = (bid - GX)*256 + tid;
    if(i < E) atomicAdd(&deg[ei[E+i]], 1);
  } else {
    int t2 = (bid - GX - GD)*256 + tid;
    if(t2 < GG*FF){
      int j = t2 >> 4, f = t2 & 15;
      float s = 0.f;
      for(int k=0;k<HH;k++) s += gcn_w[f*HH+k]*w_ih[j*HH+k];
      m1F[t2] = __half_as_ushort(__float2half(s));
    } else if (t2 < GG*FF + GG){
      int j = t2 - GG*FF;
      float s = b_ih[j];
      for(int k=0;k<HH;k++) s += gcn_b[k]*w_ih[j*HH+k];
      c1[j] = s;
    }
    if(t2 < GG*HH){
      whhF[t2] = __half_as_ushort(__float2half(w_hh[t2]));
    }
  }
}

// ---------------- scan: offsets + dinv ----------------
__global__ __launch_bounds__(1024) void k_scan(const int* __restrict__ deg, int* __restrict__ offsets,
                                               float* __restrict__ dinv, int N){
  __shared__ int s[1024];
  int tid = threadIdx.x;
  int CH = (N + 1023) >> 10;
  int lo = tid*CH, hi = min(N, lo+CH);
  int sum=0;
  for(int j=lo;j<hi;j++){
    int d = deg[j];
    dinv[j] = rsqrtf((float)d + 1.0f);
    sum += d;
  }
  s[tid]=sum; __syncthreads();
  for(int o=1;o<1024;o<<=1){
    int v = 0;
    if(tid>=o) v = s[tid-o];
    __syncthreads();
    s[tid] += v;
    __syncthreads();
  }
  int run = s[tid]-sum;
  for(int j=lo;j<hi;j++){ offsets[j]=run; run += deg[j]; }
  if(tid==1023) offsets[N]=s[1023];
}

__global__ void k_fill(const int* __restrict__ ei, int E, const float* __restrict__ dinv,
                       const int* __restrict__ offsets, int* __restrict__ counters,
                       int2* __restrict__ csr2){
  int i = blockIdx.x*blockDim.x + threadIdx.x;
  if(i>=E) return;
  int s = ei[i], d = ei[E+i];
  int slot = offsets[d] + atomicAdd(&counters[d], 1);
  csr2[slot] = make_int2(s, __float_as_int(dinv[s]*dinv[d]));
}

// ---------------- aggregation v7: 2 requests/edge (uint4+uint2), 8 edges/iter ----------------
// Row = 768 B: halfs [0,256) as 32 x uint4 (lane lh), halfs [256,384) as 32 x uint2.
// half-wave h handles edges j+2k+h (k=0..3) per iter: 8 row-loads + 4 csr in flight/lane.
__global__ __launch_bounds__(256)
void k_aggTh(const ushort* __restrict__ xTh, const int* __restrict__ offsets,
             const int2* __restrict__ csr2, const float* __restrict__ dinv,
             ushort* __restrict__ aggF, int N){
  int wid = (blockIdx.x*blockDim.x + threadIdx.x) >> 6;
  if(wid >= N) return;
  const int l = threadIdx.x & 63;
  const int half = l >> 5, lh = l & 31;
  const int n = wid;

  float aA[8] = {0.f,0.f,0.f,0.f,0.f,0.f,0.f,0.f};
  float aB[4] = {0.f,0.f,0.f,0.f};

  const int lo = offsets[n], hi = offsets[n+1];
  for(int j = lo; j < hi; j += 8){
    int j0 = j     + half;
    int j1 = j + 2 + half;
    int j2 = j + 4 + half;
    int j3 = j + 6 + half;
    bool k0 = j0 < hi, k1 = j1 < hi, k2 = j2 < hi, k3 = j3 < hi;
    int2 c0 = csr2[k0 ? j0 : lo];
    int2 c1 = csr2[k1 ? j1 : lo];
    int2 c2 = csr2[k2 ? j2 : lo];
    int2 c3 = csr2[k3 ? j3 : lo];
    float w0 = k0 ? __int_as_float(c0.y) : 0.f;
    float w1 = k1 ? __int_as_float(c1.y) : 0.f;
    float w2 = k2 ? __int_as_float(c2.y) : 0.f;
    float w3 = k3 ? __int_as_float(c3.y) : 0.f;
    const ushort* r0 = xTh + (size_t)c0.x*384;
    const ushort* r1 = xTh + (size_t)c1.x*384;
    const ushort* r2 = xTh + (size_t)c2.x*384;
    const ushort* r3 = xTh + (size_t)c3.x*384;
    uint4 A0 = *(const uint4*)(r0 + lh*8);
    uint4 A1 = *(const uint4*)(r1 + lh*8);
    uint4 A2 = *(const uint4*)(r2 + lh*8);
    uint4 A3 = *(const uint4*)(r3 + lh*8);
    uint2 B0 = *(const uint2*)(r0 + 256 + lh*4);
    uint2 B1 = *(const uint2*)(r1 + 256 + lh*4);
    uint2 B2 = *(const uint2*)(r2 + 256 + lh*4);
    uint2 B3 = *(const uint2*)(r3 + 256 + lh*4);
    acc8(aA, A0, w0); acc4(aB, B0, w0);
    acc8(aA, A1, w1); acc4(aB, B1, w1);
    acc8(aA, A2, w2); acc4(aB, B2, w2);
    acc8(aA, A3, w3); acc4(aB, B3, w3);
  }
  // reduce the two halves (lane lh <-> lh+32 hold identical positions)
  #pragma unroll
  for(int k=0;k<8;k++) aA[k] += __shfl_xor(aA[k], 32, 64);
  #pragma unroll
  for(int k=0;k<4;k++) aB[k] += __shfl_xor(aB[k], 32, 64);

  if(half == 0){
    float sn = dinv[n]; sn *= sn;
    const ushort* rS = xTh + (size_t)n*384;
    uint4 AS = *(const uint4*)(rS + lh*8);
    uint2 BS = *(const uint2*)(rS + 256 + lh*4);
    acc8(aA, AS, sn); acc4(aB, BS, sn);

    // A part: halfs u = 8*lh + k -> t = lh>>1, f0 = (lh&1)*8
    {
      int tA = lh >> 1, fA = (lh & 1)*8;
      size_t oA = ((size_t)tA*N + n)*FF + fA;
      ushort4 h0, h1;
      h0.x = __half_as_ushort(__float2half(aA[0]));
      h0.y = __half_as_ushort(__float2half(aA[1]));
      h0.z = __half_as_ushort(__float2half(aA[2]));
      h0.w = __half_as_ushort(__float2half(aA[3]));
      h1.x = __half_as_ushort(__float2half(aA[4]));
      h1.y = __half_as_ushort(__float2half(aA[5]));
      h1.z = __half_as_ushort(__float2half(aA[6]));
      h1.w = __half_as_ushort(__float2half(aA[7]));
      *(ushort4*)(aggF + oA)     = h0;
      *(ushort4*)(aggF + oA + 4) = h1;
    }
    // B part: halfs u = 256 + 4*lh -> t = u>>4, f = u&15
    {
      int uB = 256 + 4*lh;
      int tB = uB >> 4, fB = uB & 15;
      size_t oB = ((size_t)tB*N + n)*FF + fB;
      ushort4 hB;
      hB.x = __half_as_ushort(__float2half(aB[0]));
      hB.y = __half_as_ushort(__float2half(aB[1]));
      hB.z = __half_as_ushort(__float2half(aB[2]));
      hB.w = __half_as_ushort(__float2half(aB[3]));
      *(ushort4*)(aggF + oB) = hB;
    }
  }
}

// ---------------- GRU v5: 16 nodes/block, 4 waves split over channels ----------------
__global__ __launch_bounds__(256, 6)
void k_gru5(const ushort* __restrict__ aggF,
            const ushort* __restrict__ whhF, const ushort* __restrict__ m1F,
            const float* __restrict__ c1, const float* __restrict__ bhh,
            const float* __restrict__ lin_w, const float* __restrict__ lin_b,
            float* __restrict__ out, int N, int P){
  __shared__ __align__(16) uint hb[2][512];   // 2 x (16 nodes x 64 ch f16) = 4 KB
  const int tid = threadIdx.x;
  const int l = tid & 63, w = tid >> 6;
  const int nd = l & 15, g = l >> 4;
  const int node = blockIdx.x*16 + nd;
  const int nodec = min(node, N-1);
  const int chB = 16*w;

  const f16x8 zf = (f16x8){0,0,0,0,0,0,0,0};
  f16x8 ar0,ar1,az0,az1,an0,an1, mr,mz,mn;
  {
    const int rr =        chB + nd;
    const int rz =  HH  + chB + nd;
    const int rn = 2*HH + chB + nd;
    ar0 = *(const f16x8*)(whhF + rr*HH      + g*8);
    ar1 = *(const f16x8*)(whhF + rr*HH + 32 + g*8);
    az0 = *(const f16x8*)(whhF + rz*HH      + g*8);
    az1 = *(const f16x8*)(whhF + rz*HH + 32 + g*8);
    an0 = *(const f16x8*)(whhF + rn*HH      + g*8);
    an1 = *(const f16x8*)(whhF + rn*HH + 32 + g*8);
    mr = zf; mz = zf; mn = zf;
    if(g < 2){
      mr = *(const f16x8*)(m1F + rr*FF + g*8);
      mz = *(const f16x8*)(m1F + rz*FF + g*8);
      mn = *(const f16x8*)(m1F + rn*FF + g*8);
    } else if(g == 2){
      mr[0] = (_Float16)(c1[rr] + bhh[rr]);
      mz[0] = (_Float16)(c1[rz] + bhh[rz]);
      mn[0] = (_Float16)(c1[rn]);
    }
  }
  float4 bb = *(const float4*)(bhh + 2*HH + chB + g*4);

  float hreg[4] = {0.f,0.f,0.f,0.f};

  for(int i=tid; i<512; i+=256) hb[0][i]=0u;

  f16x8 cAg = zf;
  if(g==2) cAg[0] = (_Float16)1.0f;
  if(g < 2) cAg = *(const f16x8*)(aggF + (size_t)nodec*FF + g*8);

  const int swz = (nd & 7) << 2;
  __syncthreads();

  for(int t=0; t<TT; t++){
    const uint* cb = hb[t & 1];
    uint* nb = hb[(t & 1) ^ 1];

    f16x8 hB0 = *(const f16x8*)(cb + nd*32 + ((g*4)      ^ swz));
    f16x8 hB1 = *(const f16x8*)(cb + nd*32 + ((16 + g*4) ^ swz));

    f16x8 pAg = cAg;
    if(g < 2 && t+1 < TT)
      pAg = *(const f16x8*)(aggF + (size_t)(t+1)*N*FF + (size_t)nodec*FF + g*8);

    f32x4 R  = {0.f,0.f,0.f,0.f};
    f32x4 Z  = {0.f,0.f,0.f,0.f};
    f32x4 Nh = {0.f,0.f,0.f,0.f};
    f32x4 Ni = {0.f,0.f,0.f,0.f};
    R  = __builtin_amdgcn_mfma_f32_16x16x32_f16(ar0, hB0, R , 0,0,0);
    R  = __builtin_amdgcn_mfma_f32_16x16x32_f16(ar1, hB1, R , 0,0,0);
    R  = __builtin_amdgcn_mfma_f32_16x16x32_f16(mr,  cAg, R , 0,0,0);
    Z  = __builtin_amdgcn_mfma_f32_16x16x32_f16(az0, hB0, Z , 0,0,0);
    Z  = __builtin_amdgcn_mfma_f32_16x16x32_f16(az1, hB1, Z , 0,0,0);
    Z  = __builtin_amdgcn_mfma_f32_16x16x32_f16(mz,  cAg, Z , 0,0,0);
    Nh = __builtin_amdgcn_mfma_f32_16x16x32_f16(an0, hB0, Nh, 0,0,0);
    Nh = __builtin_amdgcn_mfma_f32_16x16x32_f16(an1, hB1, Nh, 0,0,0);
    Ni = __builtin_amdgcn_mfma_f32_16x16x32_f16(mn,  cAg, Ni, 0,0,0);

    const float bbv[4] = {bb.x, bb.y, bb.z, bb.w};
    #pragma unroll
    for(int i=0;i<4;i++){
      float r_ = sigmoid_f(R[i]);
      float z_ = sigmoid_f(Z[i]);
      float nn = tanh_f(Ni[i] + r_*(Nh[i] + bbv[i]));
      hreg[i] = nn + z_*(hreg[i] - nn);
    }
    uint2 pk;
    pk.x = pack_h2(hreg[0], hreg[1]);
    pk.y = pack_h2(hreg[2], hreg[3]);
    *(uint2*)(nb + nd*32 + ((8*w + 2*g) ^ swz)) = pk;

    cAg = pAg;
    __syncthreads();
  }

  // ---- fused linear head ----
  float* hs = (float*)hb;
  #pragma unroll
  for(int i=0;i<4;i++) hs[nd*64 + chB + g*4 + i] = hreg[i];
  __syncthreads();
  if(tid < 16*P){
    int ndl = tid & 15, p = tid >> 4;
    int node2 = blockIdx.x*16 + ndl;
    if(node2 < N){
      float acc = lin_b[p];
      const float* hrow = hs + ndl*64;
      #pragma unroll
      for(int q=0;q<16;q++){
        float4 v = *(const float4*)(hrow + q*4);
        float4 lw = *(const float4*)(lin_w + p*HH + q*4);
        acc += v.x*lw.x + v.y*lw.y + v.z*lw.z + v.w*lw.w;
      }
      out[(size_t)p*N + node2] = acc;
    }
  }
}

extern "C" void kernel_launch(void* const* d_in, const int* in_sizes, int n_in,
                              void* d_out, int out_size, void* d_ws, size_t ws_size,
                              hipStream_t stream){
  const float* x     = (const float*)d_in[0];
  const float* gcn_w = (const float*)d_in[2];
  const float* gcn_b = (const float*)d_in[3];
  const float* w_ih  = (const float*)d_in[4];
  const float* w_hh  = (const float*)d_in[5];
  const float* b_ih  = (const float*)d_in[6];
  const float* b_hh  = (const float*)d_in[7];
  const float* lin_w = (const float*)d_in[8];
  const float* lin_b = (const float*)d_in[9];
  const int*   ei    = (const int*)d_in[10];
  const int E = in_sizes[10]/2;
  const int N = in_sizes[0]/(TT*FF);
  const int P = in_sizes[9];

  char* wsp = (char*)d_ws;
  auto alloc = [&](size_t bytes)->void*{ void* p = wsp; wsp += (bytes + 255) & ~(size_t)255; return p; };
  int*    deg      = (int*)   alloc((size_t)2*N*4);
  int*    counters = deg + N;
  int*    offsets  = (int*)   alloc((size_t)(N+1)*4);
  float*  dinv     = (float*) alloc((size_t)N*4);
  int2*   csr2     = (int2*)  alloc((size_t)E*8);
  ushort* xTh      = (ushort*)alloc((size_t)N*384*2);
  ushort* aggF     = (ushort*)alloc((size_t)TT*N*FF*2);
  ushort* m1F      = (ushort*)alloc((size_t)GG*FF*2);
  float*  c1       = (float*) alloc((size_t)GG*4);
  ushort* whhF     = (ushort*)alloc((size_t)GG*HH*2);

  hipMemsetAsync(deg, 0, (size_t)2*N*4, stream);

  const int GX = (N + 15)/16;
  const int GD = (E + 255)/256;
  const int GP = (GG*HH + 255)/256;
  k_pre  <<<GX + GD + GP, 256, 0, stream>>>(x, xTh, ei, E, deg,
                                            gcn_w, gcn_b, w_ih, b_ih, w_hh,
                                            m1F, c1, whhF, N, GX, GD);
  k_scan <<<1, 1024, 0, stream>>>(deg, offsets, dinv, N);
  k_fill <<<(E+255)/256, 256, 0, stream>>>(ei, E, dinv, offsets, counters, csr2);
  k_aggTh<<<(N+3)/4, 256, 0, stream>>>(xTh, offsets, csr2, dinv, aggF, N);
  k_gru5 <<<(N+15)/16, 256, 0, stream>>>(aggF, whhF, m1F, c1, b_hh,
                                         lin_w, lin_b, (float*)d_out, N, P);
}